// Round 4
// baseline (147.449 us; speedup 1.0000x reference)
//
#include <hip/hip_runtime.h>

#define NPTS   150000
#define KOBJ   192
#define PBLK   128      // partial-reduction blocks in k_prep
#define PREP_T 512
#define MAIN_PB 586     // ceil(NPTS/256) point-blocks in k_main
#define KHALF  96       // k_main: each block does one half of the 192 objects
#define MAIN_GRID (MAIN_PB * 2)

__device__ __forceinline__ float clipb(float b) {
    return fminf(fmaxf(b, 1e-4f), 1.0f - 1e-4f);
}

// ws layout (bytes):
// pKey : u64 [PBLK*KOBJ]   @ 0
// pW   : f32 [PBLK*KOBJ]   @ OFF_PW
// pP0  : f32 [PBLK*KOBJ]   @ OFF_PP0
// pP1  : f32 [PBLK*KOBJ]   @ OFF_PP1
// scal : f32 [16]          @ OFF_SCAL  {0 att,1 rep,2 noiseS,3 noiseC,4 mbS,5 payS,6 cntObj}
// tick : u32               @ OFF_TICK
// xaq  : float4 [KOBJ]     @ OFF_XAQ
#define OFF_PW   (PBLK * KOBJ * 8)
#define OFF_PP0  (OFF_PW  + PBLK * KOBJ * 4)
#define OFF_PP1  (OFF_PP0 + PBLK * KOBJ * 4)
#define OFF_SCAL (OFF_PP1 + PBLK * KOBJ * 4)
#define OFF_TICK (OFF_SCAL + 64)
#define OFF_XAQ  (OFF_TICK + 16)

// ---------------------------------------------------------------------------
// Kernel 1: per-point prep -> per-block partials (LDS reduce, no global
// atomics except 2 noise adds per block).
// ---------------------------------------------------------------------------
__global__ __launch_bounds__(PREP_T) void k_prep(
        const float* __restrict__ pred_beta,
        const float* __restrict__ pred_energy,
        const float* __restrict__ pred_pos,
        const int*   __restrict__ t_idx,
        const float* __restrict__ t_energy,
        const float* __restrict__ t_pos,
        unsigned long long* __restrict__ pKey,
        float* __restrict__ pW,
        float* __restrict__ pP0,
        float* __restrict__ pP1,
        float* __restrict__ scal) {
    __shared__ unsigned long long sKey[KOBJ];
    __shared__ float sW[KOBJ], sP0[KOBJ], sP1[KOBJ];
    __shared__ float sNs[PREP_T / 64], sNc[PREP_T / 64];
    const int tid = threadIdx.x;
    if (tid < KOBJ) { sKey[tid] = 0ULL; sW[tid] = 0.f; sP0[tid] = 0.f; sP1[tid] = 0.f; }
    __syncthreads();

    float nS = 0.f, nC = 0.f;
    for (int i = blockIdx.x * PREP_T + tid; i < NPTS; i += PBLK * PREP_T) {
        const float b = clipb(pred_beta[i]);
        const int   t = t_idx[i];
        if (t >= 0) {
            const float a = atanhf(b);
            const float w = a * a;
            // argmax key: higher beta wins; tie -> lower index (np.argmax)
            const unsigned long long key =
                ((unsigned long long)__float_as_uint(b) << 32) |
                (unsigned long long)(0xFFFFFFFFu - (unsigned)i);
            atomicMax(&sKey[t], key);

            const float pe = pred_energy[i], te = t_energy[i];
            const float el = (te - pe) * (te - pe) / (te * te);
            const float pp0 = pred_pos[2 * i],  pp1 = pred_pos[2 * i + 1];
            const float tp0 = t_pos[2 * i],     tp1 = t_pos[2 * i + 1];
            const float pl = (tp0 - pp0) * (tp0 - pp0) / (tp0 * tp0)
                           + (tp1 - pp1) * (tp1 - pp1) / (tp1 * tp1);
            atomicAdd(&sW[t],  w);
            atomicAdd(&sP0[t], w * el);
            atomicAdd(&sP1[t], w * pl);
        } else {
            nS += b; nC += 1.f;
        }
    }
    // noise: wave reduce then block reduce
    for (int off = 32; off > 0; off >>= 1) {
        nS += __shfl_down(nS, off);
        nC += __shfl_down(nC, off);
    }
    if ((tid & 63) == 0) { sNs[tid >> 6] = nS; sNc[tid >> 6] = nC; }
    __syncthreads();

    // flush full partial row (includes zeros -> no global memset needed)
    if (tid < KOBJ) {
        const int o = blockIdx.x * KOBJ + tid;
        pKey[o] = sKey[tid];
        pW[o]   = sW[tid];
        pP0[o]  = sP0[tid];
        pP1[o]  = sP1[tid];
    }
    if (tid == 0) {
        float s = 0.f, c = 0.f;
        for (int w = 0; w < PREP_T / 64; ++w) { s += sNs[w]; c += sNc[w]; }
        if (s != 0.f || c != 0.f) { atomicAdd(&scal[2], s); atomicAdd(&scal[3], c); }
    }
}

// ---------------------------------------------------------------------------
// Kernel 2: per-object reduce of partials; gather alpha; min_b / pay terms.
// grid = KOBJ blocks x 64 lanes.
// ---------------------------------------------------------------------------
__global__ __launch_bounds__(64) void k_objs(
        const float* __restrict__ pred_beta,
        const float* __restrict__ pred_ccoords,
        const float* __restrict__ t_time,
        const unsigned long long* __restrict__ pKey,
        const float* __restrict__ pW,
        const float* __restrict__ pP0,
        const float* __restrict__ pP1,
        float4* __restrict__ xaq,
        float* __restrict__ scal) {
    const int k = blockIdx.x, lane = threadIdx.x;
    unsigned long long best = 0ULL;
    float w = 0.f, p0 = 0.f, p1 = 0.f;
    for (int p = lane; p < PBLK; p += 64) {
        const int o = p * KOBJ + k;
        const unsigned long long kk = pKey[o];
        if (kk > best) best = kk;
        w += pW[o]; p0 += pP0[o]; p1 += pP1[o];
    }
    for (int off = 32; off > 0; off >>= 1) {
        const unsigned long long ob = __shfl_down(best, off);
        if (ob > best) best = ob;
        w  += __shfl_down(w,  off);
        p0 += __shfl_down(p0, off);
        p1 += __shfl_down(p1, off);
    }
    if (lane == 0) {
        float4 v = make_float4(0.f, 0.f, 0.f, 0.f);
        if (best != 0ULL) {
            const unsigned ai = 0xFFFFFFFFu - (unsigned)(best & 0xFFFFFFFFull);
            const float b = clipb(pred_beta[ai]);
            const float a = atanhf(b);
            v.x = pred_ccoords[3 * ai];
            v.y = pred_ccoords[3 * ai + 1];
            v.z = pred_ccoords[3 * ai + 2];
            v.w = (a * a + 0.5f) * t_time[ai];   // q_alpha (0 if no object)
            atomicAdd(&scal[4], 1.0f - b);                   // sum(1-beta_alpha)
            atomicAdd(&scal[5], (p0 + p1) / (w + 1e-9f));    // sum pay_k
            atomicAdd(&scal[6], 1.0f);                       // n_obj
        }
        xaq[k] = v;
    }
}

// ---------------------------------------------------------------------------
// Kernel 3: N x K main loop (att + rep) + folded final combine.
// grid = MAIN_PB point-blocks x 2 k-halves.
// ---------------------------------------------------------------------------
__global__ __launch_bounds__(256) void k_main(
        const float* __restrict__ pred_beta,
        const float* __restrict__ pred_ccoords,
        const int*   __restrict__ t_idx,
        const float* __restrict__ t_time,
        const float4* __restrict__ xaq,
        float* __restrict__ scal,
        unsigned int* __restrict__ tick,
        float* __restrict__ out) {
    __shared__ float4 sA[KOBJ];
    const int tid = threadIdx.x;
    if (tid < KOBJ) sA[tid] = xaq[tid];
    __syncthreads();

    const int half = blockIdx.x & 1;
    const int k0   = half * KHALF;
    const int i    = (blockIdx.x >> 1) * 256 + tid;

    float rep = 0.f, att = 0.f;
    if (i < NPTS) {
        const float x0 = pred_ccoords[3 * i];
        const float x1 = pred_ccoords[3 * i + 1];
        const float x2 = pred_ccoords[3 * i + 2];
        const float b  = clipb(pred_beta[i]);
        const float a  = atanhf(b);
        const float q  = (a * a + 0.5f) * t_time[i];
        const int own  = t_idx[i];

        float r0 = 0.f, r1 = 0.f, r2 = 0.f, r3 = 0.f;
        #pragma unroll 4
        for (int kk = k0; kk < k0 + KHALF; kk += 4) {
            const float4 A = sA[kk];
            const float4 B = sA[kk + 1];
            const float4 C = sA[kk + 2];
            const float4 D = sA[kk + 3];
            {
                const float d0 = x0 - A.x, d1 = x1 - A.y, d2 = x2 - A.z;
                r0 += fmaxf(1.0f - sqrtf(d0 * d0 + d1 * d1 + d2 * d2 + 1e-9f), 0.f) * A.w;
            }
            {
                const float d0 = x0 - B.x, d1 = x1 - B.y, d2 = x2 - B.z;
                r1 += fmaxf(1.0f - sqrtf(d0 * d0 + d1 * d1 + d2 * d2 + 1e-9f), 0.f) * B.w;
            }
            {
                const float d0 = x0 - C.x, d1 = x1 - C.y, d2 = x2 - C.z;
                r2 += fmaxf(1.0f - sqrtf(d0 * d0 + d1 * d1 + d2 * d2 + 1e-9f), 0.f) * C.w;
            }
            {
                const float d0 = x0 - D.x, d1 = x1 - D.y, d2 = x2 - D.z;
                r3 += fmaxf(1.0f - sqrtf(d0 * d0 + d1 * d1 + d2 * d2 + 1e-9f), 0.f) * D.w;
            }
        }
        rep = (r0 + r1) + (r2 + r3);
        if (own >= k0 && own < k0 + KHALF) {
            const float4 O = sA[own];
            const float d0 = x0 - O.x, d1 = x1 - O.y, d2 = x2 - O.z;
            const float dd = d0 * d0 + d1 * d1 + d2 * d2;
            rep -= fmaxf(1.0f - sqrtf(dd + 1e-9f), 0.f) * O.w;
            att  = dd * O.w;
        }
        rep *= q; att *= q;
    }

    for (int off = 32; off > 0; off >>= 1) {
        rep += __shfl_down(rep, off);
        att += __shfl_down(att, off);
    }
    __shared__ float wr[4], wa[4];
    const int wid = tid >> 6, lane = tid & 63;
    if (lane == 0) { wr[wid] = rep; wa[wid] = att; }
    __syncthreads();
    if (tid == 0) {
        atomicAdd(&scal[0], wa[0] + wa[1] + wa[2] + wa[3]);
        atomicAdd(&scal[1], wr[0] + wr[1] + wr[2] + wr[3]);
        __threadfence();
        const unsigned old = atomicAdd(tick, 1u);
        if (old == MAIN_GRID - 1) {
            // last block: combine (coherent reads via atomic RMW of +0)
            const float attS = atomicAdd(&scal[0], 0.f);
            const float repS = atomicAdd(&scal[1], 0.f);
            const float nS   = atomicAdd(&scal[2], 0.f);
            const float nC   = atomicAdd(&scal[3], 0.f);
            const float mbS  = atomicAdd(&scal[4], 0.f);
            const float payS = atomicAdd(&scal[5], 0.f);
            const float cnt  = atomicAdd(&scal[6], 0.f);
            const float n    = (float)NPTS;
            const float nobj = fmaxf(cnt, 1.0f);
            out[0] = attS / n + repS / n + nS / fmaxf(nC, 1.0f)
                   + mbS / nobj + payS / nobj;
        }
    }
}

extern "C" void kernel_launch(void* const* d_in, const int* in_sizes, int n_in,
                              void* d_out, int out_size, void* d_ws, size_t ws_size,
                              hipStream_t stream) {
    const float* pred_beta    = (const float*)d_in[0];
    const float* pred_ccoords = (const float*)d_in[1];
    const float* pred_energy  = (const float*)d_in[2];
    const float* pred_pos     = (const float*)d_in[3];
    const int*   t_idx        = (const int*)  d_in[6];
    const float* t_energy     = (const float*)d_in[7];
    const float* t_pos        = (const float*)d_in[8];
    const float* t_time       = (const float*)d_in[9];

    char* ws = (char*)d_ws;
    unsigned long long* pKey = (unsigned long long*)ws;
    float*        pW   = (float*)(ws + OFF_PW);
    float*        pP0  = (float*)(ws + OFF_PP0);
    float*        pP1  = (float*)(ws + OFF_PP1);
    float*        scal = (float*)(ws + OFF_SCAL);
    unsigned int* tick = (unsigned int*)(ws + OFF_TICK);
    float4*       xaq  = (float4*)(ws + OFF_XAQ);

    // zero only scal + ticket (partials are fully overwritten by k_prep)
    hipMemsetAsync(ws + OFF_SCAL, 0, OFF_XAQ - OFF_SCAL, stream);

    k_prep<<<PBLK, PREP_T, 0, stream>>>(pred_beta, pred_energy, pred_pos,
                                        t_idx, t_energy, t_pos,
                                        pKey, pW, pP0, pP1, scal);
    k_objs<<<KOBJ, 64, 0, stream>>>(pred_beta, pred_ccoords, t_time,
                                    pKey, pW, pP0, pP1, xaq, scal);
    k_main<<<MAIN_GRID, 256, 0, stream>>>(pred_beta, pred_ccoords, t_idx, t_time,
                                          xaq, scal, tick, (float*)d_out);
}

// Round 6
// 131.130 us; speedup vs baseline: 1.1244x; 1.1244x over previous
//
#include <hip/hip_runtime.h>

#define NPTS   150000
#define KOBJ   192
#define PBLK   256      // k_prep blocks (= partial rows)
#define PREP_T 512
#define NREP   8        // replicas for wsum/pay global atomics
#define MAIN_B 586      // ceil(NPTS/256)

__device__ __forceinline__ float clipb(float b) {
    return fminf(fmaxf(b, 1e-4f), 1.0f - 1e-4f);
}

// ws layout (bytes):
// pKey : u64 [KOBJ*PBLK]  @ 0          (object-major: pKey[k*PBLK + blk])  393216
// repW : f32 [NREP*KOBJ]  @ OFF_REPW   6144
// repP : f32 [NREP*KOBJ]  @ OFF_REPP   6144
// scal : f32 [16]         @ OFF_SCAL   {0 att,1 rep,2 noiseS,3 noiseC,4 mbS,5 payS,6 nobj}
// tick : u32 [4]          @ OFF_TICK
// xaq  : float4 [KOBJ]    @ OFF_XAQ
#define OFF_REPW (KOBJ * PBLK * 8)
#define OFF_REPP (OFF_REPW + NREP * KOBJ * 4)
#define OFF_SCAL (OFF_REPP + NREP * KOBJ * 4)
#define OFF_TICK (OFF_SCAL + 64)
#define OFF_XAQ  (OFF_TICK + 16)

// ---------------------------------------------------------------------------
// Kernel 1: per-point prep. Native u32 LDS atomics only.
//  pass A: atomicMax(beta_bits) per object + LDS sums of w, w*(el+pl); noise in regs
//  pass B: atomicMin(index) among threads holding the winning bits
//  flush : per-block argmax key row (object-major); sums via replicated global atomics
// ---------------------------------------------------------------------------
__global__ __launch_bounds__(PREP_T) void k_prep(
        const float* __restrict__ pred_beta,
        const float* __restrict__ pred_energy,
        const float* __restrict__ pred_pos,
        const int*   __restrict__ t_idx,
        const float* __restrict__ t_energy,
        const float* __restrict__ t_pos,
        unsigned long long* __restrict__ pKey,
        float* __restrict__ repW,
        float* __restrict__ repP,
        float* __restrict__ scal) {
    __shared__ unsigned sBits[KOBJ], sIdx[KOBJ];
    __shared__ float sW[KOBJ], sP[KOBJ];
    __shared__ float sNs[PREP_T / 64], sNc[PREP_T / 64];
    const int tid = threadIdx.x;
    if (tid < KOBJ) { sBits[tid] = 0u; sIdx[tid] = 0xFFFFFFFFu; sW[tid] = 0.f; sP[tid] = 0.f; }
    __syncthreads();

    float nS = 0.f, nC = 0.f;
    const int i0 = blockIdx.x * PREP_T + tid;
    for (int i = i0; i < NPTS; i += PBLK * PREP_T) {
        const float b = clipb(pred_beta[i]);
        const int   t = t_idx[i];
        if (t >= 0) {
            atomicMax(&sBits[t], __float_as_uint(b));
            const float a = atanhf(b);
            const float w = a * a;
            const float pe = pred_energy[i], te = t_energy[i];
            const float el = (te - pe) * (te - pe) / (te * te);
            const float pp0 = pred_pos[2 * i],  pp1 = pred_pos[2 * i + 1];
            const float tp0 = t_pos[2 * i],     tp1 = t_pos[2 * i + 1];
            const float pl = (tp0 - pp0) * (tp0 - pp0) / (tp0 * tp0)
                           + (tp1 - pp1) * (tp1 - pp1) / (tp1 * tp1);
            atomicAdd(&sW[t], w);
            atomicAdd(&sP[t], w * (el + pl));
        } else {
            nS += b; nC += 1.f;
        }
    }
    __syncthreads();
    // pass B: first-index tie-break among winners (exact np.argmax semantics)
    for (int i = i0; i < NPTS; i += PBLK * PREP_T) {
        const int t = t_idx[i];
        if (t >= 0 && __float_as_uint(clipb(pred_beta[i])) == sBits[t])
            atomicMin(&sIdx[t], (unsigned)i);
    }
    // noise: wave reduce then block reduce
    for (int off = 32; off > 0; off >>= 1) {
        nS += __shfl_down(nS, off);
        nC += __shfl_down(nC, off);
    }
    if ((tid & 63) == 0) { sNs[tid >> 6] = nS; sNc[tid >> 6] = nC; }
    __syncthreads();

    if (tid < KOBJ) {
        // empty object: bits=0, idx=0xFFFFFFFF -> key = 0 exactly
        const unsigned long long key =
            ((unsigned long long)sBits[tid] << 32) |
            (unsigned long long)(0xFFFFFFFFu - sIdx[tid]);
        pKey[(size_t)tid * PBLK + blockIdx.x] = key;
        const float w = sW[tid];
        if (w != 0.f) {
            const int r = (blockIdx.x & (NREP - 1)) * KOBJ + tid;
            atomicAdd(&repW[r], w);
            atomicAdd(&repP[r], sP[tid]);
        }
    }
    if (tid == 0) {
        float s = 0.f, c = 0.f;
        for (int w = 0; w < PREP_T / 64; ++w) { s += sNs[w]; c += sNc[w]; }
        if (c != 0.f) { atomicAdd(&scal[2], s); atomicAdd(&scal[3], c); }
    }
}

// ---------------------------------------------------------------------------
// Kernel 2: per-object reduce (coalesced row read), alpha gather, min_b/pay.
// grid = KOBJ blocks x 64 lanes.
// ---------------------------------------------------------------------------
__global__ __launch_bounds__(64) void k_objs(
        const float* __restrict__ pred_beta,
        const float* __restrict__ pred_ccoords,
        const float* __restrict__ t_time,
        const unsigned long long* __restrict__ pKey,
        const float* __restrict__ repW,
        const float* __restrict__ repP,
        float4* __restrict__ xaq,
        float* __restrict__ scal) {
    const int k = blockIdx.x, lane = threadIdx.x;
    const unsigned long long* row = pKey + (size_t)k * PBLK;
    unsigned long long best = 0ULL;
    #pragma unroll
    for (int p = lane; p < PBLK; p += 64) {
        const unsigned long long v = row[p];
        if (v > best) best = v;
    }
    float w = 0.f, pay = 0.f;
    if (lane < NREP) { w = repW[lane * KOBJ + k]; pay = repP[lane * KOBJ + k]; }
    for (int off = 32; off > 0; off >>= 1) {
        const unsigned long long ob = __shfl_down(best, off);
        if (ob > best) best = ob;
        w   += __shfl_down(w,   off);
        pay += __shfl_down(pay, off);
    }
    if (lane == 0) {
        float4 v = make_float4(0.f, 0.f, 0.f, 0.f);
        if (best != 0ULL) {
            const unsigned ai = 0xFFFFFFFFu - (unsigned)(best & 0xFFFFFFFFull);
            const float b = clipb(pred_beta[ai]);
            const float a = atanhf(b);
            v.x = pred_ccoords[3 * ai];
            v.y = pred_ccoords[3 * ai + 1];
            v.z = pred_ccoords[3 * ai + 2];
            v.w = (a * a + 0.5f) * t_time[ai];   // q_alpha (0 if no object)
            atomicAdd(&scal[4], 1.0f - b);
            atomicAdd(&scal[5], pay / (w + 1e-9f));
            atomicAdd(&scal[6], 1.0f);
        }
        xaq[k] = v;
    }
}

// ---------------------------------------------------------------------------
// Kernel 3: N x K main loop (round-2 proven structure: scalar LDS arrays,
// broadcast reads) + 4 static accumulators + raw v_sqrt_f32 + folded combine.
// ---------------------------------------------------------------------------
__device__ __forceinline__ float rep_term(float x0, float x1, float x2,
                                          float a0, float a1, float a2, float qw) {
    const float d0 = x0 - a0, d1 = x1 - a1, d2 = x2 - a2;
    const float dd = d0 * d0 + d1 * d1 + d2 * d2 + 1e-9f;
    return fmaxf(1.0f - __builtin_amdgcn_sqrtf(dd), 0.f) * qw;
}

__global__ __launch_bounds__(256) void k_main(
        const float* __restrict__ pred_beta,
        const float* __restrict__ pred_ccoords,
        const int*   __restrict__ t_idx,
        const float* __restrict__ t_time,
        const float4* __restrict__ xaq,
        float* __restrict__ scal,
        unsigned int* __restrict__ tick,
        float* __restrict__ out) {
    __shared__ float s0[KOBJ], s1[KOBJ], s2[KOBJ], sq[KOBJ];
    const int tid = threadIdx.x;
    if (tid < KOBJ) {
        const float4 v = xaq[tid];
        s0[tid] = v.x; s1[tid] = v.y; s2[tid] = v.z; sq[tid] = v.w;
    }
    __syncthreads();

    const int i = blockIdx.x * 256 + tid;
    float rep = 0.f, att = 0.f;
    if (i < NPTS) {
        const float x0 = pred_ccoords[3 * i];
        const float x1 = pred_ccoords[3 * i + 1];
        const float x2 = pred_ccoords[3 * i + 2];
        const float b  = clipb(pred_beta[i]);
        const float a  = atanhf(b);
        const float q  = (a * a + 0.5f) * t_time[i];
        const int own  = t_idx[i];

        float r0 = 0.f, r1 = 0.f, r2 = 0.f, r3 = 0.f;
        #pragma unroll 4
        for (int kk = 0; kk < KOBJ; kk += 4) {
            r0 += rep_term(x0, x1, x2, s0[kk],     s1[kk],     s2[kk],     sq[kk]);
            r1 += rep_term(x0, x1, x2, s0[kk + 1], s1[kk + 1], s2[kk + 1], sq[kk + 1]);
            r2 += rep_term(x0, x1, x2, s0[kk + 2], s1[kk + 2], s2[kk + 2], sq[kk + 2]);
            r3 += rep_term(x0, x1, x2, s0[kk + 3], s1[kk + 3], s2[kk + 3], sq[kk + 3]);
        }
        rep = (r0 + r1) + (r2 + r3);
        if (own >= 0) {
            const float d0 = x0 - s0[own], d1 = x1 - s1[own], d2 = x2 - s2[own];
            const float dd = d0 * d0 + d1 * d1 + d2 * d2;
            rep -= fmaxf(1.0f - __builtin_amdgcn_sqrtf(dd + 1e-9f), 0.f) * sq[own];
            att  = dd * sq[own];
        }
        rep *= q; att *= q;
    }

    for (int off = 32; off > 0; off >>= 1) {
        rep += __shfl_down(rep, off);
        att += __shfl_down(att, off);
    }
    __shared__ float wr[4], wa[4];
    const int wid = tid >> 6, lane = tid & 63;
    if (lane == 0) { wr[wid] = rep; wa[wid] = att; }
    __syncthreads();
    if (tid == 0) {
        atomicAdd(&scal[0], wa[0] + wa[1] + wa[2] + wa[3]);
        atomicAdd(&scal[1], wr[0] + wr[1] + wr[2] + wr[3]);
        __threadfence();
        const unsigned old = atomicAdd(tick, 1u);
        if (old == MAIN_B - 1) {
            const float attS = atomicAdd(&scal[0], 0.f);
            const float repS = atomicAdd(&scal[1], 0.f);
            const float nS   = atomicAdd(&scal[2], 0.f);
            const float nC   = atomicAdd(&scal[3], 0.f);
            const float mbS  = atomicAdd(&scal[4], 0.f);
            const float payS = atomicAdd(&scal[5], 0.f);
            const float cnt  = atomicAdd(&scal[6], 0.f);
            const float n    = (float)NPTS;
            const float nobj = fmaxf(cnt, 1.0f);
            out[0] = attS / n + repS / n + nS / fmaxf(nC, 1.0f)
                   + mbS / nobj + payS / nobj;
        }
    }
}

extern "C" void kernel_launch(void* const* d_in, const int* in_sizes, int n_in,
                              void* d_out, int out_size, void* d_ws, size_t ws_size,
                              hipStream_t stream) {
    const float* pred_beta    = (const float*)d_in[0];
    const float* pred_ccoords = (const float*)d_in[1];
    const float* pred_energy  = (const float*)d_in[2];
    const float* pred_pos     = (const float*)d_in[3];
    const int*   t_idx        = (const int*)  d_in[6];
    const float* t_energy     = (const float*)d_in[7];
    const float* t_pos        = (const float*)d_in[8];
    const float* t_time       = (const float*)d_in[9];

    char* ws = (char*)d_ws;
    unsigned long long* pKey = (unsigned long long*)ws;
    float*        repW = (float*)(ws + OFF_REPW);
    float*        repP = (float*)(ws + OFF_REPP);
    float*        scal = (float*)(ws + OFF_SCAL);
    unsigned int* tick = (unsigned int*)(ws + OFF_TICK);
    float4*       xaq  = (float4*)(ws + OFF_XAQ);

    // zero repW/repP/scal/tick (pKey fully overwritten; xaq fully overwritten)
    hipMemsetAsync(ws + OFF_REPW, 0, OFF_XAQ - OFF_REPW, stream);

    k_prep<<<PBLK, PREP_T, 0, stream>>>(pred_beta, pred_energy, pred_pos,
                                        t_idx, t_energy, t_pos,
                                        pKey, repW, repP, scal);
    k_objs<<<KOBJ, 64, 0, stream>>>(pred_beta, pred_ccoords, t_time,
                                    pKey, repW, repP, xaq, scal);
    k_main<<<MAIN_B, 256, 0, stream>>>(pred_beta, pred_ccoords, t_idx, t_time,
                                       xaq, scal, tick, (float*)d_out);
}

// Round 7
// 120.214 us; speedup vs baseline: 1.2266x; 1.0908x over previous
//
#include <hip/hip_runtime.h>

#define NPTS    150000
#define KOBJ    192
#define PBLK    256      // k_prep blocks (= partial rows); also == nz partial count
#define PREP_T  512
#define MAIN_PB 586      // ceil(NPTS/256)
#define KH      96       // k_main: objects per k-half
#define MAIN_GRID (MAIN_PB * 2)

__device__ __forceinline__ float clipb(float b) {
    return fminf(fmaxf(b, 1e-4f), 1.0f - 1e-4f);
}

// ws layout (bytes) — NOTHING needs pre-zeroing (all fully written each launch):
// pKey  : u64 [KOBJ*PBLK]   @ 0           object-major rows      393216
// pW    : f32 [KOBJ*PBLK]   @ OFF_PW                             196608
// pP    : f32 [KOBJ*PBLK]   @ OFF_PP                             196608
// nzS   : f32 [PBLK]        @ OFF_NZS
// nzC   : f32 [PBLK]        @ OFF_NZC
// mbA   : f32 [KOBJ]        @ OFF_MB
// payA  : f32 [KOBJ]        @ OFF_PAY
// exA   : f32 [KOBJ]        @ OFF_EX
// xaq   : float4 [KOBJ]     @ OFF_XAQ
// attP  : f32 [MAIN_GRID]   @ OFF_ATTP
// repP  : f32 [MAIN_GRID]   @ OFF_REPP
// tick  : u32               @ OFF_TICK   (zeroed by every k_prep block)
#define OFF_PW   (KOBJ * PBLK * 8)
#define OFF_PP   (OFF_PW  + KOBJ * PBLK * 4)
#define OFF_NZS  (OFF_PP  + KOBJ * PBLK * 4)
#define OFF_NZC  (OFF_NZS + PBLK * 4)
#define OFF_MB   (OFF_NZC + PBLK * 4)
#define OFF_PAY  (OFF_MB  + KOBJ * 4)
#define OFF_EX   (OFF_PAY + KOBJ * 4)
#define OFF_XAQ  (OFF_EX  + KOBJ * 4)
#define OFF_ATTP (OFF_XAQ + KOBJ * 16)
#define OFF_REPP (OFF_ATTP + MAIN_GRID * 4)
#define OFF_TICK (OFF_REPP + MAIN_GRID * 4)

// ---------------------------------------------------------------------------
// Kernel 1: per-point prep -> per-block partial rows. No global atomics.
// ---------------------------------------------------------------------------
__global__ __launch_bounds__(PREP_T) void k_prep(
        const float* __restrict__ pred_beta,
        const float* __restrict__ pred_energy,
        const float* __restrict__ pred_pos,
        const int*   __restrict__ t_idx,
        const float* __restrict__ t_energy,
        const float* __restrict__ t_pos,
        unsigned long long* __restrict__ pKey,
        float* __restrict__ pW,
        float* __restrict__ pP,
        float* __restrict__ nzS,
        float* __restrict__ nzC,
        unsigned int* __restrict__ tick) {
    __shared__ unsigned sBits[KOBJ], sIdx[KOBJ];
    __shared__ float sW[KOBJ], sP[KOBJ];
    __shared__ float sNs[PREP_T / 64], sNc[PREP_T / 64];
    const int tid = threadIdx.x;
    if (tid < KOBJ) { sBits[tid] = 0u; sIdx[tid] = 0xFFFFFFFFu; sW[tid] = 0.f; sP[tid] = 0.f; }
    __syncthreads();

    float nS = 0.f, nC = 0.f;
    const int i0 = blockIdx.x * PREP_T + tid;
    for (int i = i0; i < NPTS; i += PBLK * PREP_T) {
        const float b = clipb(pred_beta[i]);
        const int   t = t_idx[i];
        if (t >= 0) {
            atomicMax(&sBits[t], __float_as_uint(b));     // native u32 LDS atomic
            const float a = atanhf(b);
            const float w = a * a;
            const float pe = pred_energy[i], te = t_energy[i];
            const float el = (te - pe) * (te - pe) / (te * te);
            const float pp0 = pred_pos[2 * i],  pp1 = pred_pos[2 * i + 1];
            const float tp0 = t_pos[2 * i],     tp1 = t_pos[2 * i + 1];
            const float pl = (tp0 - pp0) * (tp0 - pp0) / (tp0 * tp0)
                           + (tp1 - pp1) * (tp1 - pp1) / (tp1 * tp1);
            atomicAdd(&sW[t], w);
            atomicAdd(&sP[t], w * (el + pl));
        } else {
            nS += b; nC += 1.f;
        }
    }
    __syncthreads();
    // pass B: first-index tie-break among max-beta holders (np.argmax semantics)
    for (int i = i0; i < NPTS; i += PBLK * PREP_T) {
        const int t = t_idx[i];
        if (t >= 0 && __float_as_uint(clipb(pred_beta[i])) == sBits[t])
            atomicMin(&sIdx[t], (unsigned)i);
    }
    for (int off = 32; off > 0; off >>= 1) {
        nS += __shfl_down(nS, off);
        nC += __shfl_down(nC, off);
    }
    if ((tid & 63) == 0) { sNs[tid >> 6] = nS; sNc[tid >> 6] = nC; }
    __syncthreads();

    if (tid < KOBJ) {
        // empty object: bits=0, idx=0xFFFFFFFF -> key == 0 exactly
        const unsigned long long key =
            ((unsigned long long)sBits[tid] << 32) |
            (unsigned long long)(0xFFFFFFFFu - sIdx[tid]);
        const size_t o = (size_t)tid * PBLK + blockIdx.x;
        pKey[o] = key;
        pW[o]   = sW[tid];
        pP[o]   = sP[tid];
    }
    if (tid == 0) {
        float s = 0.f, c = 0.f;
        for (int w = 0; w < PREP_T / 64; ++w) { s += sNs[w]; c += sNc[w]; }
        nzS[blockIdx.x] = s;
        nzC[blockIdx.x] = c;
        *tick = 0u;   // all blocks store 0 (benign); visible to k_main at kernel boundary
    }
}

// ---------------------------------------------------------------------------
// Kernel 2: per-object reduce (coalesced rows); alpha gather; mb/pay/exists.
// grid = KOBJ blocks x 64 lanes. No atomics.
// ---------------------------------------------------------------------------
__global__ __launch_bounds__(64) void k_objs(
        const float* __restrict__ pred_beta,
        const float* __restrict__ pred_ccoords,
        const float* __restrict__ t_time,
        const unsigned long long* __restrict__ pKey,
        const float* __restrict__ pW,
        const float* __restrict__ pP,
        float4* __restrict__ xaq,
        float* __restrict__ mbA,
        float* __restrict__ payA,
        float* __restrict__ exA) {
    const int k = blockIdx.x, lane = threadIdx.x;
    const size_t row = (size_t)k * PBLK;
    unsigned long long best = 0ULL;
    float w = 0.f, pay = 0.f;
    #pragma unroll
    for (int p = lane; p < PBLK; p += 64) {
        const unsigned long long v = pKey[row + p];
        if (v > best) best = v;
        w   += pW[row + p];
        pay += pP[row + p];
    }
    for (int off = 32; off > 0; off >>= 1) {
        const unsigned long long ob = __shfl_down(best, off);
        if (ob > best) best = ob;
        w   += __shfl_down(w,   off);
        pay += __shfl_down(pay, off);
    }
    if (lane == 0) {
        float4 v = make_float4(0.f, 0.f, 0.f, 0.f);
        float mb = 0.f, pk = 0.f, ex = 0.f;
        if (best != 0ULL) {
            const unsigned ai = 0xFFFFFFFFu - (unsigned)(best & 0xFFFFFFFFull);
            const float b = clipb(pred_beta[ai]);
            const float a = atanhf(b);
            v.x = pred_ccoords[3 * ai];
            v.y = pred_ccoords[3 * ai + 1];
            v.z = pred_ccoords[3 * ai + 2];
            v.w = (a * a + 0.5f) * t_time[ai];   // q_alpha (0 if no object)
            mb = 1.0f - b;
            pk = pay / (w + 1e-9f);
            ex = 1.f;
        }
        xaq[k] = v; mbA[k] = mb; payA[k] = pk; exA[k] = ex;
    }
}

// ---------------------------------------------------------------------------
// Kernel 3: N x KH main loop (2 k-halves per point block) + last-block combine.
// ---------------------------------------------------------------------------
__device__ __forceinline__ float rep_term(float x0, float x1, float x2,
                                          float a0, float a1, float a2, float qw) {
    const float d0 = x0 - a0, d1 = x1 - a1, d2 = x2 - a2;
    const float dd = d0 * d0 + d1 * d1 + d2 * d2 + 1e-9f;
    return fmaxf(1.0f - __builtin_amdgcn_sqrtf(dd), 0.f) * qw;
}

__device__ __forceinline__ float block_sum(float v, float* red, int tid) {
    for (int off = 32; off > 0; off >>= 1) v += __shfl_down(v, off);
    if ((tid & 63) == 0) red[tid >> 6] = v;
    __syncthreads();
    const float r = red[0] + red[1] + red[2] + red[3];
    __syncthreads();
    return r;
}

__global__ __launch_bounds__(256) void k_main(
        const float* __restrict__ pred_beta,
        const float* __restrict__ pred_ccoords,
        const int*   __restrict__ t_idx,
        const float* __restrict__ t_time,
        const float4* __restrict__ xaq,
        const float* __restrict__ nzS,
        const float* __restrict__ nzC,
        const float* __restrict__ mbA,
        const float* __restrict__ payA,
        const float* __restrict__ exA,
        float* __restrict__ attP,
        float* __restrict__ repP,
        unsigned int* __restrict__ tick,
        float* __restrict__ out) {
    __shared__ float s0[KH], s1[KH], s2[KH], sq[KH];
    __shared__ float red[4];
    __shared__ int sLast;
    const int tid = threadIdx.x;
    const int k0  = (blockIdx.x & 1) * KH;
    if (tid < KH) {
        const float4 v = xaq[k0 + tid];
        s0[tid] = v.x; s1[tid] = v.y; s2[tid] = v.z; sq[tid] = v.w;
    }
    __syncthreads();

    const int i = (blockIdx.x >> 1) * 256 + tid;
    float rep = 0.f, att = 0.f;
    if (i < NPTS) {
        const float x0 = pred_ccoords[3 * i];
        const float x1 = pred_ccoords[3 * i + 1];
        const float x2 = pred_ccoords[3 * i + 2];
        const float b  = clipb(pred_beta[i]);
        const float a  = atanhf(b);
        const float q  = (a * a + 0.5f) * t_time[i];
        const int oj   = t_idx[i] - k0;   // own index within this half, if any

        float r0 = 0.f, r1 = 0.f, r2 = 0.f, r3 = 0.f;
        #pragma unroll 4
        for (int kk = 0; kk < KH; kk += 4) {
            r0 += rep_term(x0, x1, x2, s0[kk],     s1[kk],     s2[kk],     sq[kk]);
            r1 += rep_term(x0, x1, x2, s0[kk + 1], s1[kk + 1], s2[kk + 1], sq[kk + 1]);
            r2 += rep_term(x0, x1, x2, s0[kk + 2], s1[kk + 2], s2[kk + 2], sq[kk + 2]);
            r3 += rep_term(x0, x1, x2, s0[kk + 3], s1[kk + 3], s2[kk + 3], sq[kk + 3]);
        }
        rep = (r0 + r1) + (r2 + r3);
        if (oj >= 0 && oj < KH) {
            const float d0 = x0 - s0[oj], d1 = x1 - s1[oj], d2 = x2 - s2[oj];
            const float dd = d0 * d0 + d1 * d1 + d2 * d2;
            rep -= fmaxf(1.0f - __builtin_amdgcn_sqrtf(dd + 1e-9f), 0.f) * sq[oj];
            att  = dd * sq[oj];
        }
        rep *= q; att *= q;
    }

    for (int off = 32; off > 0; off >>= 1) {
        rep += __shfl_down(rep, off);
        att += __shfl_down(att, off);
    }
    __shared__ float wr[4], wa[4];
    const int wid = tid >> 6;
    if ((tid & 63) == 0) { wr[wid] = rep; wa[wid] = att; }
    __syncthreads();
    if (tid == 0) {
        attP[blockIdx.x] = wa[0] + wa[1] + wa[2] + wa[3];
        repP[blockIdx.x] = wr[0] + wr[1] + wr[2] + wr[3];
        __threadfence();
        const unsigned old = atomicAdd(tick, 1u);
        sLast = (old == MAIN_GRID - 1) ? 1 : 0;
    }
    __syncthreads();
    if (sLast) {
        // final combine: atomic-reads for intra-kernel partials (XCD coherence),
        // plain reads for prior-kernel outputs (kernel-boundary flushed).
        float aS = 0.f, rS = 0.f;
        for (int b = tid; b < MAIN_GRID; b += 256) {
            aS += atomicAdd(&attP[b], 0.f);
            rS += atomicAdd(&repP[b], 0.f);
        }
        float mb = 0.f, pay = 0.f, ex = 0.f;
        if (tid < KOBJ) { mb = mbA[tid]; pay = payA[tid]; ex = exA[tid]; }
        const float ns = nzS[tid];   // PBLK == 256 == blockDim
        const float nc = nzC[tid];

        const float attS = block_sum(aS, red, tid);
        const float repS = block_sum(rS, red, tid);
        const float mbS  = block_sum(mb, red, tid);
        const float payS = block_sum(pay, red, tid);
        const float exS  = block_sum(ex, red, tid);
        const float nSs  = block_sum(ns, red, tid);
        const float nCs  = block_sum(nc, red, tid);
        if (tid == 0) {
            const float n    = (float)NPTS;
            const float nobj = fmaxf(exS, 1.0f);
            out[0] = attS / n + repS / n + nSs / fmaxf(nCs, 1.0f)
                   + mbS / nobj + payS / nobj;
        }
    }
}

extern "C" void kernel_launch(void* const* d_in, const int* in_sizes, int n_in,
                              void* d_out, int out_size, void* d_ws, size_t ws_size,
                              hipStream_t stream) {
    const float* pred_beta    = (const float*)d_in[0];
    const float* pred_ccoords = (const float*)d_in[1];
    const float* pred_energy  = (const float*)d_in[2];
    const float* pred_pos     = (const float*)d_in[3];
    const int*   t_idx        = (const int*)  d_in[6];
    const float* t_energy     = (const float*)d_in[7];
    const float* t_pos        = (const float*)d_in[8];
    const float* t_time       = (const float*)d_in[9];

    char* ws = (char*)d_ws;
    unsigned long long* pKey = (unsigned long long*)ws;
    float*        pW   = (float*)(ws + OFF_PW);
    float*        pP   = (float*)(ws + OFF_PP);
    float*        nzS  = (float*)(ws + OFF_NZS);
    float*        nzC  = (float*)(ws + OFF_NZC);
    float*        mbA  = (float*)(ws + OFF_MB);
    float*        payA = (float*)(ws + OFF_PAY);
    float*        exA  = (float*)(ws + OFF_EX);
    float4*       xaq  = (float4*)(ws + OFF_XAQ);
    float*        attP = (float*)(ws + OFF_ATTP);
    float*        repP = (float*)(ws + OFF_REPP);
    unsigned int* tick = (unsigned int*)(ws + OFF_TICK);

    // no memset: every ws word used is fully written each launch
    // (pKey/pW/pP/nzS/nzC by k_prep, xaq/mbA/payA/exA by k_objs,
    //  attP/repP by k_main, tick zeroed by k_prep).
    k_prep<<<PBLK, PREP_T, 0, stream>>>(pred_beta, pred_energy, pred_pos,
                                        t_idx, t_energy, t_pos,
                                        pKey, pW, pP, nzS, nzC, tick);
    k_objs<<<KOBJ, 64, 0, stream>>>(pred_beta, pred_ccoords, t_time,
                                    pKey, pW, pP, xaq, mbA, payA, exA);
    k_main<<<MAIN_GRID, 256, 0, stream>>>(pred_beta, pred_ccoords, t_idx, t_time,
                                          xaq, nzS, nzC, mbA, payA, exA,
                                          attP, repP, tick, (float*)d_out);
}